// Round 12
// baseline (153.647 us; speedup 1.0000x reference)
//
#include <hip/hip_runtime.h>
#include <math.h>

#define NBINS 10
#define NB    32
#define HH    512
#define WW    512
#define HC    64
#define WC    64
#define NBR   63
#define NBC   63
#define EPS2F 1e-10f      // EPS^2, EPS=1e-5

// ---------------------------------------------------------------------------
// K1: fused Sobel + binning + 8x8 mean pool -> cell[n][bin][cy][cx] (f32)
// Block = (cy, n): 256 threads / 4 waves, 4 threads per cell (2 px-rows each).
// __launch_bounds__(256,4): VGPR cap 128 (was 48 with default bounds — the
// round-10 regression: R[4][10] couldn't stay resident, compiler sank the
// LDS loads to use points -> per-pixel lgkmcnt stalls, VALUBusy 65->40%).
// With 128 VGPRs the window stays in registers; pixel loop is pure VALU.
// Bin decision numerics BYTE-IDENTICAL to passing rounds 3-10:
//   exact cross-product sector finder, guard band 3.2e-5*mag, fallback to
//   (float)atan2(double,double) f32-emulation; fast path cem=(flm+1)%10.
// ---------------------------------------------------------------------------
__global__ __launch_bounds__(256, 4) void k_cellhist(const float* __restrict__ img,
                                                     float* __restrict__ cell) {
    const int cy = blockIdx.x;   // 0..63
    const int n  = blockIdx.y;   // 0..31
    const int t  = threadIdx.x;  // 0..255

    __shared__ float lds[10][516];

    const float* im = img + (size_t)n * HH * WW;
    const int gy0 = cy * 8 - 1;
    for (int idx = t; idx < 10 * 514; idx += 256) {
        int r  = idx / 514;
        int c  = idx - r * 514;          // lds col 0..513, img col = c-1
        int gr = gy0 + r, gc = c - 1;
        float v = 0.0f;
        if ((unsigned)gr < HH && (unsigned)gc < WW) v = im[gr * WW + gc];
        lds[r][c] = v;
    }
    __syncthreads();

    const float pi32 = (float)M_PI;          // 0x40490FDB
    // sin/cos(k*pi/10), k=1..4
    const float S1 = 0.30901699f, C1 = 0.95105652f;
    const float S2 = 0.58778525f, C2 = 0.80901699f;
    const float S3 = 0.80901699f, C3 = 0.58778525f;
    const float S4 = 0.95105652f, C4 = 0.30901699f;

    const int cc  = t >> 2;                  // cell 0..63
    const int sub = t & 3;
    const int r0  = 1 + 2 * sub;             // pixel rows r0, r0+1 of the strip

    // window registers: rows r0-1..r0+2, cols cc*8 .. cc*8+9 (wide DS reads)
    float R[4][10];
#pragma unroll
    for (int r = 0; r < 4; ++r) {
        const float* rowp = &lds[r0 - 1 + r][cc * 8];
        float4 v0 = *(const float4*)(rowp);
        float4 v1 = *(const float4*)(rowp + 4);
        float2 v2 = *(const float2*)(rowp + 8);
        R[r][0] = v0.x; R[r][1] = v0.y; R[r][2] = v0.z; R[r][3] = v0.w;
        R[r][4] = v1.x; R[r][5] = v1.y; R[r][6] = v1.z; R[r][7] = v1.w;
        R[r][8] = v2.x; R[r][9] = v2.y;
    }

    float hist[NBINS];
#pragma unroll
    for (int b = 0; b < NBINS; ++b) hist[b] = 0.0f;

#pragma unroll
    for (int ry = 0; ry < 2; ++ry) {
#pragma unroll
        for (int k = 0; k < 8; ++k) {
            float a  = R[ry    ][k    ];
            float b  = R[ry    ][k + 1];
            float c  = R[ry    ][k + 2];
            float d  = R[ry + 1][k    ];
            float f  = R[ry + 1][k + 2];
            float g  = R[ry + 2][k    ];
            float h  = R[ry + 2][k + 1];
            float i2 = R[ry + 2][k + 2];
            // identical accumulation order to the passing round-3 kernel
            float gA = a;
            gA = gA - c;
            gA = gA + 2.0f * d;
            gA = gA - 2.0f * f;
            gA = gA + g;
            gA = gA - i2;
            float gB = a;
            gB = gB + 2.0f * b;
            gB = gB + c;
            gB = gB - g;
            gB = gB - 2.0f * h;
            gB = gB - i2;

            float mag = __builtin_amdgcn_sqrtf(gA * gA + gB * gB);

            // exact sector via cross products (quadrant-reduced)
            float y = fabsf(gA), x = fabsf(gB);
            float cr1 = fmaf(y, C1, -(x * S1));
            float cr2 = fmaf(y, C2, -(x * S2));
            float cr3 = fmaf(y, C3, -(x * S3));
            float cr4 = fmaf(y, C4, -(x * S4));
            int idx = (cr1 > 0.0f) + (cr2 > 0.0f) + (cr3 > 0.0f) + (cr4 > 0.0f);
            float minc = fminf(fminf(y, x),
                               fminf(fminf(fabsf(cr1), fabsf(cr2)),
                                     fminf(fabsf(cr3), fabsf(cr4))));
            int flm, cem;
            if (minc > 3.2e-5f * mag) {
                bool same = (gA >= 0.0f) == (gB >= 0.0f);
                flm = same ? idx : 9 - idx;
                cem = flm + 1; if (cem == NBINS) cem = 0;   // == (flm+1)%10 here
            } else {
                // exact f32-emulation fallback (round-3 verified, bit-identical)
                float phase = (float)atan2((double)gA, (double)gB);
                float pb = phase / pi32;
                pb = pb * 10.0f;
                int fl = (int)floorf(pb);
                int ce = (int)ceilf(pb);
                flm = fl % NBINS; if (flm < 0) flm += NBINS;   // Python %
                cem = ce % NBINS; if (cem < 0) cem += NBINS;
            }
            hist[flm] += mag;
            hist[cem] += 1.0f - mag;
        }
    }

    // merge the 4 per-thread partials of each cell (lanes 4c..4c+3)
#pragma unroll
    for (int b = 0; b < NBINS; ++b) {
        hist[b] += __shfl_xor(hist[b], 1);
        hist[b] += __shfl_xor(hist[b], 2);
    }

    // write cell (each sub writes bins with (b&3)==sub, coalesced in cc)
#pragma unroll
    for (int bb = 0; bb < NBINS; ++bb) {
        if ((bb & 3) == sub)
            cell[(((size_t)n * NBINS + bb) * HC + cy) * WC + cc] = hist[bb] * 0.015625f;
    }
}

// ---------------------------------------------------------------------------
// K2: block per i (63 blocks, 256 thr = 64 j-lanes x 4 subs).
// Pass 1: s[i][j] = sum over 320 slices of the 2x2 window of cell^2
//         -> w = 1/sqrt(s+eps^2)  (block reduce, no atomics, no memset)
// Pass 2: s2[i][j] = sum of min(cell*w, 0.2)^2 (re-read, L2-hot)
//         -> inv2 = 1/sqrt(s2+eps^2).  Writes inv1[ij], inv2[ij].
// ---------------------------------------------------------------------------
__global__ __launch_bounds__(256) void k_norm(const float* __restrict__ cell,
                                              float* __restrict__ inv1,
                                              float* __restrict__ inv2) {
    const int i   = blockIdx.x;     // 0..62
    const int t   = threadIdx.x;
    const int j   = t & 63;         // 0..63 (j==63 lanes masked at write)
    const int sub = t >> 6;         // 0..3
    const int j1  = (j < 63) ? 1 : 0;   // clamp so loads stay in-bounds

    __shared__ float red[4][64];
    __shared__ float wsh[64];

    float acc = 0.0f;
    for (int s0 = sub; s0 < NB * NBINS; s0 += 4) {
        const float* base = cell + ((size_t)s0 * HC + i) * WC + j;
        float v00 = base[0],  v01 = base[j1];
        float v10 = base[WC], v11 = base[WC + j1];
        acc = fmaf(v00, v00, acc);
        acc = fmaf(v01, v01, acc);
        acc = fmaf(v10, v10, acc);
        acc = fmaf(v11, v11, acc);
    }
    red[sub][j] = acc;
    __syncthreads();
    if (sub == 0) {
        float s = red[0][j] + red[1][j] + red[2][j] + red[3][j];
        wsh[j] = 1.0f / sqrtf(s + EPS2F);
    }
    __syncthreads();
    const float w = wsh[j];

    float acc2 = 0.0f;
    for (int s0 = sub; s0 < NB * NBINS; s0 += 4) {
        const float* base = cell + ((size_t)s0 * HC + i) * WC + j;
        float v00 = base[0],  v01 = base[j1];
        float v10 = base[WC], v11 = base[WC + j1];
        v00 = fminf(v00 * w, 0.2f); acc2 = fmaf(v00, v00, acc2);
        v01 = fminf(v01 * w, 0.2f); acc2 = fmaf(v01, v01, acc2);
        v10 = fminf(v10 * w, 0.2f); acc2 = fmaf(v10, v10, acc2);
        v11 = fminf(v11 * w, 0.2f); acc2 = fmaf(v11, v11, acc2);
    }
    red[sub][j] = acc2;
    __syncthreads();
    if (sub == 0 && j < NBC) {
        float s2 = red[0][j] + red[1][j] + red[2][j] + red[3][j];
        inv1[i * NBC + j] = w;
        inv2[i * NBC + j] = 1.0f / sqrtf(s2 + EPS2F);
    }
}

// ---------------------------------------------------------------------------
// K3: final write out[n][bin][di][dj][i][j] — pure streaming f32
// ---------------------------------------------------------------------------
__global__ void k_out(const float* __restrict__ cell,
                      const float* __restrict__ inv1,
                      const float* __restrict__ inv2,
                      float* __restrict__ out) {
    int idx = blockIdx.x * blockDim.x + threadIdx.x;
    const int total = NB * NBINS * 2 * 2 * NBR * NBC;
    if (idx >= total) return;
    int ij  = idx % (NBR * NBC);
    int tmp = idx / (NBR * NBC);
    int j   = ij % NBC;
    int i   = ij / NBC;
    int dj  = tmp % 2;   tmp /= 2;
    int di  = tmp % 2;   tmp /= 2;
    int b   = tmp % NBINS;
    int n   = tmp / NBINS;
    float v = cell[(((size_t)n * NBINS + b) * HC + i + di) * WC + j + dj] * inv1[ij];
    v = fminf(v, 0.2f);
    out[idx] = v * inv2[ij];
}

// ---------------------------------------------------------------------------
extern "C" void kernel_launch(void* const* d_in, const int* in_sizes, int n_in,
                              void* d_out, int out_size, void* d_ws, size_t ws_size,
                              hipStream_t stream) {
    const float* img = (const float*)d_in[0];   // (32,1,512,512) f32
    float* out = (float*)d_out;

    float* cell = (float*)d_ws;                           // 32*10*64*64
    float* inv1 = cell + (size_t)NB * NBINS * HC * WC;    // 63*63
    float* inv2 = inv1 + NBR * NBC;                       // 63*63

    hipLaunchKernelGGL(k_cellhist, dim3(HC, NB), dim3(256), 0, stream, img, cell);
    hipLaunchKernelGGL(k_norm, dim3(NBR), dim3(256), 0, stream, cell, inv1, inv2);
    const int total = NB * NBINS * 2 * 2 * NBR * NBC;
    hipLaunchKernelGGL(k_out, dim3((total + 255) / 256), dim3(256), 0, stream,
                       cell, inv1, inv2, out);
}

// Round 13
// 134.773 us; speedup vs baseline: 1.1400x; 1.1400x over previous
//
#include <hip/hip_runtime.h>
#include <math.h>

#define NBINS 10
#define NB    32
#define HH    512
#define WW    512
#define HC    64
#define WC    64
#define NBR   63
#define NBC   63
#define EPS2F 1e-10f      // EPS^2, EPS=1e-5

// ---------------------------------------------------------------------------
// K1: fused Sobel + binning + 8x8 mean pool -> cell[n][bin][cy][cx] (f32)
// BYTE-IDENTICAL to the round-12 kernel that measured 48 us (no Q-atomic).
// Bin decision numerics identical to passing rounds 3-12.
// ---------------------------------------------------------------------------
__global__ __launch_bounds__(256, 4) void k_cellhist(const float* __restrict__ img,
                                                     float* __restrict__ cell) {
    const int cy = blockIdx.x;   // 0..63
    const int n  = blockIdx.y;   // 0..31
    const int t  = threadIdx.x;  // 0..255

    __shared__ float lds[10][516];

    const float* im = img + (size_t)n * HH * WW;
    const int gy0 = cy * 8 - 1;
    for (int idx = t; idx < 10 * 514; idx += 256) {
        int r  = idx / 514;
        int c  = idx - r * 514;          // lds col 0..513, img col = c-1
        int gr = gy0 + r, gc = c - 1;
        float v = 0.0f;
        if ((unsigned)gr < HH && (unsigned)gc < WW) v = im[gr * WW + gc];
        lds[r][c] = v;
    }
    __syncthreads();

    const float pi32 = (float)M_PI;          // 0x40490FDB
    // sin/cos(k*pi/10), k=1..4
    const float S1 = 0.30901699f, C1 = 0.95105652f;
    const float S2 = 0.58778525f, C2 = 0.80901699f;
    const float S3 = 0.80901699f, C3 = 0.58778525f;
    const float S4 = 0.95105652f, C4 = 0.30901699f;

    const int cc  = t >> 2;                  // cell 0..63
    const int sub = t & 3;
    const int r0  = 1 + 2 * sub;             // pixel rows r0, r0+1 of the strip

    // window registers: rows r0-1..r0+2, cols cc*8 .. cc*8+9 (wide DS reads)
    float R[4][10];
#pragma unroll
    for (int r = 0; r < 4; ++r) {
        const float* rowp = &lds[r0 - 1 + r][cc * 8];
        float4 v0 = *(const float4*)(rowp);
        float4 v1 = *(const float4*)(rowp + 4);
        float2 v2 = *(const float2*)(rowp + 8);
        R[r][0] = v0.x; R[r][1] = v0.y; R[r][2] = v0.z; R[r][3] = v0.w;
        R[r][4] = v1.x; R[r][5] = v1.y; R[r][6] = v1.z; R[r][7] = v1.w;
        R[r][8] = v2.x; R[r][9] = v2.y;
    }

    float hist[NBINS];
#pragma unroll
    for (int b = 0; b < NBINS; ++b) hist[b] = 0.0f;

#pragma unroll
    for (int ry = 0; ry < 2; ++ry) {
#pragma unroll
        for (int k = 0; k < 8; ++k) {
            float a  = R[ry    ][k    ];
            float b  = R[ry    ][k + 1];
            float c  = R[ry    ][k + 2];
            float d  = R[ry + 1][k    ];
            float f  = R[ry + 1][k + 2];
            float g  = R[ry + 2][k    ];
            float h  = R[ry + 2][k + 1];
            float i2 = R[ry + 2][k + 2];
            // identical accumulation order to the passing round-3 kernel
            float gA = a;
            gA = gA - c;
            gA = gA + 2.0f * d;
            gA = gA - 2.0f * f;
            gA = gA + g;
            gA = gA - i2;
            float gB = a;
            gB = gB + 2.0f * b;
            gB = gB + c;
            gB = gB - g;
            gB = gB - 2.0f * h;
            gB = gB - i2;

            float mag = __builtin_amdgcn_sqrtf(gA * gA + gB * gB);

            // exact sector via cross products (quadrant-reduced)
            float y = fabsf(gA), x = fabsf(gB);
            float cr1 = fmaf(y, C1, -(x * S1));
            float cr2 = fmaf(y, C2, -(x * S2));
            float cr3 = fmaf(y, C3, -(x * S3));
            float cr4 = fmaf(y, C4, -(x * S4));
            int idx = (cr1 > 0.0f) + (cr2 > 0.0f) + (cr3 > 0.0f) + (cr4 > 0.0f);
            float minc = fminf(fminf(y, x),
                               fminf(fminf(fabsf(cr1), fabsf(cr2)),
                                     fminf(fabsf(cr3), fabsf(cr4))));
            int flm, cem;
            if (minc > 3.2e-5f * mag) {
                bool same = (gA >= 0.0f) == (gB >= 0.0f);
                flm = same ? idx : 9 - idx;
                cem = flm + 1; if (cem == NBINS) cem = 0;   // == (flm+1)%10 here
            } else {
                // exact f32-emulation fallback (round-3 verified, bit-identical)
                float phase = (float)atan2((double)gA, (double)gB);
                float pb = phase / pi32;
                pb = pb * 10.0f;
                int fl = (int)floorf(pb);
                int ce = (int)ceilf(pb);
                flm = fl % NBINS; if (flm < 0) flm += NBINS;   // Python %
                cem = ce % NBINS; if (cem < 0) cem += NBINS;
            }
            hist[flm] += mag;
            hist[cem] += 1.0f - mag;
        }
    }

    // merge the 4 per-thread partials of each cell (lanes 4c..4c+3)
#pragma unroll
    for (int b = 0; b < NBINS; ++b) {
        hist[b] += __shfl_xor(hist[b], 1);
        hist[b] += __shfl_xor(hist[b], 2);
    }

    // write cell (each sub writes bins with (b&3)==sub, coalesced in cc)
#pragma unroll
    for (int bb = 0; bb < NBINS; ++bb) {
        if ((bb & 3) == sub)
            cell[(((size_t)n * NBINS + bb) * HC + cy) * WC + cc] = hist[bb] * 0.015625f;
    }
}

// ---------------------------------------------------------------------------
// K2: Q[i][j] = sum over (n,bin) of cell^2.  Grid (HC, 4): 256 blocks.
// 256 thr = 64 j-lanes x 4 subs; each sub streams 20 slices (coalesced in j);
// LDS-reduce the 4 subs -> ONE atomicAdd per (chunk,i,j) = 4 per address.
// ---------------------------------------------------------------------------
__global__ __launch_bounds__(256) void k_Q(const float* __restrict__ cell,
                                           float* __restrict__ Q) {
    const int i     = blockIdx.x;   // 0..63
    const int chunk = blockIdx.y;   // 0..3
    const int t     = threadIdx.x;
    const int j     = t & 63;
    const int sub   = t >> 6;       // 0..3
    float acc = 0.0f;
    const int s0 = (chunk * 4 + sub) * 20;   // 16 lanes-groups x 20 slices = 320
    for (int s = s0; s < s0 + 20; ++s) {
        float v = cell[((size_t)s * HC + i) * WC + j];
        acc = fmaf(v, v, acc);
    }
    __shared__ float red[4][64];
    red[sub][j] = acc;
    __syncthreads();
    if (sub == 0)
        atomicAdd(&Q[i * WC + j], red[0][j] + red[1][j] + red[2][j] + red[3][j]);
}

// ---------------------------------------------------------------------------
// K3: s2[i][j] = sum over (n,bin,di,dj) of min(cell*inv1, 0.2)^2
// Grid (NBR, 16) = 1008 blocks; 64j x 4sub; 5 slices/sub (20 coalesced loads);
// LDS-reduce subs -> one atomicAdd per block (16 per address).
// ---------------------------------------------------------------------------
__global__ __launch_bounds__(256) void k_s2(const float* __restrict__ cell,
                                            const float* __restrict__ Q,
                                            float* __restrict__ s2) {
    const int i     = blockIdx.x;   // 0..62
    const int chunk = blockIdx.y;   // 0..15
    const int t     = threadIdx.x;
    const int j     = t & 63;
    const int sub   = t >> 6;       // 0..3
    const int jj    = (j < NBC) ? j : (NBC - 1);   // clamp; j==63 masked at write

    float s = Q[i * WC + jj] + Q[i * WC + jj + 1] +
              Q[(i + 1) * WC + jj] + Q[(i + 1) * WC + jj + 1];
    float w = 1.0f / sqrtf(s + EPS2F);

    float acc = 0.0f;
    const int nb0 = (chunk * 4 + sub) * 5;       // 64 groups x 5 slices = 320
    for (int nb = nb0; nb < nb0 + 5; ++nb) {
        const float* base = cell + ((size_t)nb * HC + i) * WC + jj;
        float v00 = base[0],  v01 = base[1];
        float v10 = base[WC], v11 = base[WC + 1];
        v00 = fminf(v00 * w, 0.2f); acc = fmaf(v00, v00, acc);
        v01 = fminf(v01 * w, 0.2f); acc = fmaf(v01, v01, acc);
        v10 = fminf(v10 * w, 0.2f); acc = fmaf(v10, v10, acc);
        v11 = fminf(v11 * w, 0.2f); acc = fmaf(v11, v11, acc);
    }
    __shared__ float red[4][64];
    red[sub][j] = acc;
    __syncthreads();
    if (sub == 0 && j < NBC)
        atomicAdd(&s2[i * NBC + j], red[0][j] + red[1][j] + red[2][j] + red[3][j]);
}

// ---------------------------------------------------------------------------
// K4: inv1[ij] = 1/sqrt(s+eps^2), inv2[ij] = 1/sqrt(s2+eps^2)
// ---------------------------------------------------------------------------
__global__ void k_inv(const float* __restrict__ Q, const float* __restrict__ s2,
                      float* __restrict__ inv1, float* __restrict__ inv2) {
    int idx = blockIdx.x * blockDim.x + threadIdx.x;
    if (idx >= NBR * NBC) return;
    int i = idx / NBC, j = idx - i * NBC;
    float s = Q[i * WC + j] + Q[i * WC + j + 1] +
              Q[(i + 1) * WC + j] + Q[(i + 1) * WC + j + 1];
    inv1[idx] = 1.0f / sqrtf(s + EPS2F);
    inv2[idx] = 1.0f / sqrtf(s2[idx] + EPS2F);
}

// ---------------------------------------------------------------------------
// K5: final write out[n][bin][di][dj][i][j] — pure streaming f32
// ---------------------------------------------------------------------------
__global__ void k_out(const float* __restrict__ cell,
                      const float* __restrict__ inv1,
                      const float* __restrict__ inv2,
                      float* __restrict__ out) {
    int idx = blockIdx.x * blockDim.x + threadIdx.x;
    const int total = NB * NBINS * 2 * 2 * NBR * NBC;
    if (idx >= total) return;
    int ij  = idx % (NBR * NBC);
    int tmp = idx / (NBR * NBC);
    int j   = ij % NBC;
    int i   = ij / NBC;
    int dj  = tmp % 2;   tmp /= 2;
    int di  = tmp % 2;   tmp /= 2;
    int b   = tmp % NBINS;
    int n   = tmp / NBINS;
    float v = cell[(((size_t)n * NBINS + b) * HC + i + di) * WC + j + dj] * inv1[ij];
    v = fminf(v, 0.2f);
    out[idx] = v * inv2[ij];
}

// ---------------------------------------------------------------------------
extern "C" void kernel_launch(void* const* d_in, const int* in_sizes, int n_in,
                              void* d_out, int out_size, void* d_ws, size_t ws_size,
                              hipStream_t stream) {
    const float* img = (const float*)d_in[0];   // (32,1,512,512) f32
    float* out = (float*)d_out;

    float* cell = (float*)d_ws;                           // 32*10*64*64
    float* Q    = cell + (size_t)NB * NBINS * HC * WC;    // 64*64
    float* s2   = Q + HC * WC;                            // 63*63
    float* inv1 = s2 + NBR * NBC;                         // 63*63
    float* inv2 = inv1 + NBR * NBC;                       // 63*63

    // zero the two atomic accumulators (contiguous) in one async memset
    hipMemsetAsync(Q, 0, (size_t)(HC * WC + NBR * NBC) * sizeof(float), stream);
    hipLaunchKernelGGL(k_cellhist, dim3(HC, NB), dim3(256), 0, stream, img, cell);
    hipLaunchKernelGGL(k_Q, dim3(HC, 4), dim3(256), 0, stream, cell, Q);
    hipLaunchKernelGGL(k_s2, dim3(NBR, 16), dim3(256), 0, stream, cell, Q, s2);
    hipLaunchKernelGGL(k_inv, dim3(16), dim3(256), 0, stream, Q, s2, inv1, inv2);
    const int total = NB * NBINS * 2 * 2 * NBR * NBC;
    hipLaunchKernelGGL(k_out, dim3((total + 255) / 256), dim3(256), 0, stream,
                       cell, inv1, inv2, out);
}